// Round 9
// baseline (262.708 us; speedup 1.0000x reference)
//
#include <hip/hip_runtime.h>

typedef __attribute__((ext_vector_type(8))) short bhalf8;
typedef __attribute__((ext_vector_type(4))) float floatx4;

#define ALPHA_LR 0.2f

__device__ __forceinline__ unsigned short f2bf(float f) {
  union { float f; unsigned int u; } v; v.f = f;
  unsigned int r = v.u + 0x7fffu + ((v.u >> 16) & 1u);
  return (unsigned short)(r >> 16);
}
__device__ __forceinline__ float bf2f(unsigned short u) {
  union { unsigned int u; float f; } v; v.u = ((unsigned int)u) << 16;
  return v.f;
}
// async global->LDS, 16B per lane; LDS dest is wave-uniform base + lane*16
__device__ __forceinline__ void gld16(const void* g, void* l) {
  __builtin_amdgcn_global_load_lds((const __attribute__((address_space(1))) unsigned int*)g,
                                   (__attribute__((address_space(3))) unsigned int*)l,
                                   16, 0, 0);
}

// ---------------------------------------------------------------------------
// k0w: W [k][n] fp32 -> WT_hi/WT_lo bf16, k-tiled layout [ks=8][n=256][k'=32].
// Grid (16,17): by<16 = transpose blocks; by==16 = Wa blocks computing
// Wa1[k] = sum_n W[k][n] a1[n] and Wa2 (fp32, for k1's exact s1/s2 dots).
// Also re-initializes s2maxEnc[8] (ws is re-poisoned before every call).
// ---------------------------------------------------------------------------
__global__ void k0w_split(const float* __restrict__ W,
                          const float* __restrict__ a_g,
                          unsigned short* __restrict__ WThi,
                          unsigned short* __restrict__ WTlo,
                          unsigned int* __restrict__ s2maxEnc,
                          float* __restrict__ Wa) {
  const int tx = threadIdx.x, ty = threadIdx.y;
  if (blockIdx.y == 16) {
    // Wa block: k = bx*16 + ty, n-chunk = tx*16..+16
    __shared__ float r1[16][17], r2[16][17];
    const int k = blockIdx.x * 16 + ty;
    const float* wr = W + k * 256 + tx * 16;
    float p1 = 0.f, p2 = 0.f;
#pragma unroll
    for (int j = 0; j < 16; j++) {
      float w = wr[j];
      p1 += w * a_g[tx * 16 + j];
      p2 += w * a_g[256 + tx * 16 + j];
    }
    r1[ty][tx] = p1;
    r2[ty][tx] = p2;
    __syncthreads();
    if (tx == 0) {
      float v1 = 0.f, v2 = 0.f;
#pragma unroll
      for (int j = 0; j < 16; j++) { v1 += r1[ty][j]; v2 += r2[ty][j]; }
      Wa[k] = v1;
      Wa[256 + k] = v2;
    }
    return;
  }
  __shared__ float s[16][17];
  if (blockIdx.x == 0 && blockIdx.y == 0 && ty == 0 && tx < 8) s2maxEnc[tx] = 0u;
  const int n0 = blockIdx.x * 16, k0 = blockIdx.y * 16;
  s[ty][tx] = W[(k0 + ty) * 256 + n0 + tx];
  __syncthreads();
  float v = s[tx][ty];  // = W[k0+tx][n0+ty]
  const int k = k0 + tx, n = n0 + ty;
  unsigned short hi = f2bf(v);
  unsigned short lo = f2bf(v - bf2f(hi));
  const int idx = (k >> 5) * 8192 + n * 32 + (k & 31);
  WThi[idx] = hi;
  WTlo[idx] = lo;
}

// ---------------------------------------------------------------------------
// k1 v2: Wh = h @ W, TWO MFMA passes (ah*bh + ah*bl = bf16(h) x exact-W).
// The dropped al*bh term contributes |h_lo . W| ~ 0.0016 abs -- subdominant
// to WhPack's own bf16 store quantum (~0.003). s1/s2 NO LONGER come from the
// accumulators: they are exact fp32 dots h . Wa computed during A-staging
// (each wave's 64 lanes hold one full row per q -> 6-level shfl reduce,
// lane0 writes global + tracks per-wave s2max -> one encoded atomicMax).
// Al buffer, lo-split VALU, and the old dot/atomic epilogue are deleted.
// Writes WhPack bf16 [B][jt=64][f=256][j'=32]. LDS ~97 KB.
// ---------------------------------------------------------------------------
__global__ __launch_bounds__(512, 2) void k1_mfma(const float* __restrict__ h,
                                                  const unsigned short* __restrict__ Bhi_g,
                                                  const unsigned short* __restrict__ Blo_g,
                                                  const float* __restrict__ Wa,
                                                  unsigned short* __restrict__ WhPack,
                                                  float* __restrict__ s1,
                                                  float* __restrict__ s2,
                                                  unsigned int* __restrict__ s2maxEnc) {
  __shared__ unsigned short Ah[64 * 264];              // 33 KB
  __shared__ unsigned short Bh[2][8192], Bl[2][8192];  // 16 KB per buffer
  const int t = threadIdx.x;
  const long r0 = (long)blockIdx.x * 64;
  const int wave = t >> 6, lane = t & 63;

#pragma unroll
  for (int rep = 0; rep < 2; rep++) {
    const int off = wave * 1024 + rep * 512;
    gld16(Bhi_g + off + lane * 8, &Bh[0][off]);
    gld16(Blo_g + off + lane * 8, &Bl[0][off]);
  }

  // Wa fragments for this lane's column slice (constant across q)
  const int c4 = t & 63;
  const float4 wa1 = *(const float4*)(Wa + c4 * 4);
  const float4 wa2 = *(const float4*)(Wa + 256 + c4 * 4);
  float s2mx = -3.4e38f;

#pragma unroll
  for (int q = 0; q < 8; q++) {
    const int row = q * 8 + wave;  // == (q*512+t)>>6
    float4 x = *(const float4*)(h + (r0 + row) * 256 + c4 * 4);
    unsigned short hs[4] = {f2bf(x.x), f2bf(x.y), f2bf(x.z), f2bf(x.w)};
    *(ushort4*)&Ah[row * 264 + c4 * 4] = (ushort4){hs[0], hs[1], hs[2], hs[3]};
    // exact fp32 dots with Wa (s1/s2)
    float p1 = x.x * wa1.x + x.y * wa1.y + x.z * wa1.z + x.w * wa1.w;
    float p2 = x.x * wa2.x + x.y * wa2.y + x.z * wa2.z + x.w * wa2.w;
#pragma unroll
    for (int off = 1; off < 64; off <<= 1) {
      p1 += __shfl_xor(p1, off);
      p2 += __shfl_xor(p2, off);
    }
    if (lane == 0) {
      s1[r0 + row] = p1;
      s2[r0 + row] = p2;
    }
    s2mx = fmaxf(s2mx, p2);  // reduced value present on all lanes
  }
  const int b = (int)(r0 >> 11);
  if (lane == 0) {
    unsigned int u = __float_as_uint(s2mx);
    unsigned int key = (u & 0x80000000u) ? ~u : (u | 0x80000000u);
    atomicMax(s2maxEnc + b, key);
  }
  __syncthreads();

  const int wm = wave >> 2, wn = wave & 3;
  const int lhi = lane >> 4, llo = lane & 15;

  floatx4 acc[2][4];
#pragma unroll
  for (int mt = 0; mt < 2; mt++)
#pragma unroll
    for (int nt = 0; nt < 4; nt++) acc[mt][nt] = (floatx4){0.f, 0.f, 0.f, 0.f};

  for (int ks = 0; ks < 8; ks++) {
    const int cur = ks & 1, nxt = cur ^ 1, ksn = (ks + 1) & 7;
#pragma unroll
    for (int rep = 0; rep < 2; rep++) {
      const int off = wave * 1024 + rep * 512;
      gld16(Bhi_g + ksn * 8192 + off + lane * 8, &Bh[nxt][off]);
      gld16(Blo_g + ksn * 8192 + off + lane * 8, &Bl[nxt][off]);
    }

    const int k0 = ks * 32;
    bhalf8 ah[2], bh[4], bl[4];
#pragma unroll
    for (int mt = 0; mt < 2; mt++) {
      int ro = (wm * 32 + mt * 16 + llo) * 264 + k0 + lhi * 8;
      ah[mt] = *(const bhalf8*)&Ah[ro];
    }
#pragma unroll
    for (int nt = 0; nt < 4; nt++) {
      int ro = (wn * 64 + nt * 16 + llo) * 32 + lhi * 8;
      bh[nt] = *(const bhalf8*)&Bh[cur][ro];
      bl[nt] = *(const bhalf8*)&Bl[cur][ro];
    }
#pragma unroll
    for (int mt = 0; mt < 2; mt++)
#pragma unroll
      for (int nt = 0; nt < 4; nt++) {
        acc[mt][nt] = __builtin_amdgcn_mfma_f32_16x16x32_bf16(ah[mt], bh[nt], acc[mt][nt], 0, 0, 0);
        acc[mt][nt] = __builtin_amdgcn_mfma_f32_16x16x32_bf16(ah[mt], bl[nt], acc[mt][nt], 0, 0, 0);
      }
    __syncthreads();
  }

  const int jt_base = (int)((r0 & 2047) >> 5);

#pragma unroll
  for (int mt = 0; mt < 2; mt++) {
#pragma unroll
    for (int nt = 0; nt < 4; nt++) {
      int f = wn * 64 + nt * 16 + llo;
      int jt = jt_base + wm;
      ushort4 pk = (ushort4){f2bf(acc[mt][nt][0]), f2bf(acc[mt][nt][1]),
                             f2bf(acc[mt][nt][2]), f2bf(acc[mt][nt][3])};
      *(ushort4*)&WhPack[((long)((b * 64 + jt) * 256 + f)) * 32 + mt * 16 + lhi * 4] = pk;
    }
  }
}

// ---------------------------------------------------------------------------
// K3 v9 (unchanged from round 8): m97-structure GEMM, P computed into LDS,
// adj streamed directly (absorbed in the idle VMEM pipe; measured free).
// LDS 90.3 KB; grid 256 x 512 thr (1 block/CU); XCD-affine b = lin&7.
// ---------------------------------------------------------------------------
__global__ __launch_bounds__(512, 2) void k3_attn(const unsigned short* __restrict__ WhPack,
                                                  const int* __restrict__ adj,
                                                  const float* __restrict__ s1g,
                                                  const float* __restrict__ s2g,
                                                  const unsigned int* __restrict__ s2maxEnc,
                                                  float* __restrict__ out) {
  const int t = threadIdx.x;
  const int lin = blockIdx.x;
  const int b = lin & 7;  // XCD-affine: round-robin dispatch -> XCD = lin%8
  const int ig = lin >> 3;
  const long gr0 = (long)b * 2048 + ig * 64;

  const int wave = t >> 6, lane = t & 63;
  const int rg = wave >> 2, fg = wave & 3;  // wave tile: 32 rows x 64 f
  const int llo = lane & 15, lhi = lane >> 4;

  __shared__ unsigned short WhL[2][16384];  // 64 KB: [kk jt][f 256][j' 32] swz
  __shared__ unsigned short Pl[2][64 * 72]; // 18 KB: [row 64][j 64 pad 72]
  __shared__ float s2l[2048];               // 8 KB
  __shared__ float lvv[64];

  // ---- P-compute role: row pr (0..63), j-octet pq (0..7) ----
  const int pr = t >> 3;
  const int pq = t & 7;

  const float s1i = s1g[gr0 + pr];
  const unsigned int ek = s2maxEnc[b];
  const float s2max = (ek & 0x80000000u) ? __uint_as_float(ek & 0x7fffffffu)
                                         : __uint_as_float(~ek);
  const float xm = s1i + s2max;
  const float Mi = fmaxf(xm, ALPHA_LR * xm);
  // adj row segment for this thread: 8 ints at + (ptile)*64 + pq*8
  const int* arow = adj + (gr0 + pr) * 2048 + pq * 8;

  // ---- gld16 source (inverse-swizzled): lane-constant part ----
  // LDS linear L = i*4096 + wave*512 + lane*8 (ushort) -> f,granule; source
  // granule = (lane&3) ^ ((lane>>3)&3) so LDS[f][g] = global[f][g ^ (f>>1)&3]
  const int gsrc8 = (((lane & 3) ^ ((lane >> 3) & 3))) * 8;
  const unsigned short* wsrcB =
      WhPack + (long)b * 524288 + wave * 512 + (lane >> 2) * 32 + gsrc8;

  // ---- ds_read lane-constant offsets ----
  const int boff = fg * 2048 + llo * 32 + (lhi ^ ((llo >> 1) & 3)) * 8;  // B
  const int aoff = (rg * 32 + llo) * 72 + lhi * 8;                       // A

  // ---- prologue ----
  // stage s2 (whole batch) into LDS
  *(float4*)&s2l[t * 4] = *(const float4*)(s2g + (long)b * 2048 + t * 4);
  // stage Wh K-tile 0 (jt 0,1) into WhL[0]
#pragma unroll
  for (int i = 0; i < 4; i++)
    gld16(wsrcB + i * 4096, &WhL[0][i * 4096 + wave * 512]);
  // adj for P-tile 0 (used in prologue) and P-tile 1 (used at step 0)
  int4 a0A = *(const int4*)(arow);
  int4 a0B = *(const int4*)(arow + 4);
  int4 ajCA = *(const int4*)(arow + 64);
  int4 ajCB = *(const int4*)(arow + 68);
  __syncthreads();  // s2l ready; WhL[0] landed (vmcnt drain)

  float lsum = 0.f;
  {  // P tile 0 -> Pl[0]
    int am[8] = {a0A.x, a0A.y, a0A.z, a0A.w, a0B.x, a0B.y, a0B.z, a0B.w};
    float4 sA = *(const float4*)&s2l[pq * 8];
    float4 sB = *(const float4*)&s2l[pq * 8 + 4];
    float xs[8] = {sA.x, sA.y, sA.z, sA.w, sB.x, sB.y, sB.z, sB.w};
    unsigned int pk[4];
    float e[8];
#pragma unroll
    for (int q = 0; q < 8; q++) {
      float x = s1i + xs[q];
      float lk = fmaxf(x, ALPHA_LR * x);
      float ee = __expf(lk - Mi);
      ee = (am[q] > 0) ? ee : 0.f;
      lsum += ee;
      e[q] = ee;
    }
#pragma unroll
    for (int q = 0; q < 4; q++)
      asm("v_cvt_pk_bf16_f32 %0, %1, %2" : "=v"(pk[q]) : "v"(e[2 * q]), "v"(e[2 * q + 1]));
    *(uint4*)&Pl[0][pr * 72 + pq * 8] = (uint4){pk[0], pk[1], pk[2], pk[3]};
  }
  __syncthreads();  // Pl[0] visible

  floatx4 acc[2][4];
#pragma unroll
  for (int mt = 0; mt < 2; mt++)
#pragma unroll
    for (int nt = 0; nt < 4; nt++) acc[mt][nt] = (floatx4){0.f, 0.f, 0.f, 0.f};

#pragma unroll 2
  for (int step = 0; step < 32; step++) {
    const int cur = step & 1, nxt = cur ^ 1;

    // ---- issue: stage next Wh K-tile + adj for P-tile step+2 ----
    if (step < 31) {
      const long jb = (long)(step + 1) * 16384;  // (step+1)*2 jt * 8192
#pragma unroll
      for (int i = 0; i < 4; i++)
        gld16(wsrcB + jb + i * 4096, &WhL[nxt][i * 4096 + wave * 512]);
    }
    const int tp = (step < 30 ? step + 2 : 31) * 64;
    int4 ajNA = *(const int4*)(arow + tp);
    int4 ajNB = *(const int4*)(arow + tp + 4);
    __builtin_amdgcn_sched_barrier(0);

    // ---- compute P for tile step+1 -> Pl[nxt] ----
    if (step < 31) {
      int am[8] = {ajCA.x, ajCA.y, ajCA.z, ajCA.w, ajCB.x, ajCB.y, ajCB.z, ajCB.w};
      const int sbase = (step + 1) * 64 + pq * 8;
      float4 sA = *(const float4*)&s2l[sbase];
      float4 sB = *(const float4*)&s2l[sbase + 4];
      float xs[8] = {sA.x, sA.y, sA.z, sA.w, sB.x, sB.y, sB.z, sB.w};
      unsigned int pk[4];
      float e[8];
#pragma unroll
      for (int q = 0; q < 8; q++) {
        float x = s1i + xs[q];
        float lk = fmaxf(x, ALPHA_LR * x);
        float ee = __expf(lk - Mi);
        ee = (am[q] > 0) ? ee : 0.f;
        lsum += ee;
        e[q] = ee;
      }
#pragma unroll
      for (int q = 0; q < 4; q++)
        asm("v_cvt_pk_bf16_f32 %0, %1, %2" : "=v"(pk[q]) : "v"(e[2 * q]), "v"(e[2 * q + 1]));
      *(uint4*)&Pl[nxt][pr * 72 + pq * 8] = (uint4){pk[0], pk[1], pk[2], pk[3]};
    }
    ajCA = ajNA; ajCB = ajNB;

    // ---- MFMA on current buffers: kk2 x (mt2 x nt4) ----
#pragma unroll
    for (int kk = 0; kk < 2; kk++) {
      bhalf8 aF[2], bF[4];
#pragma unroll
      for (int mt = 0; mt < 2; mt++)
        aF[mt] = *(const bhalf8*)&Pl[cur][aoff + mt * 1152 + kk * 32];
#pragma unroll
      for (int nt = 0; nt < 4; nt++)
        bF[nt] = *(const bhalf8*)&WhL[cur][kk * 8192 + nt * 512 + boff];
#pragma unroll
      for (int mt = 0; mt < 2; mt++)
#pragma unroll
        for (int nt = 0; nt < 4; nt++)
          acc[mt][nt] = __builtin_amdgcn_mfma_f32_16x16x32_bf16(aF[mt], bF[nt], acc[mt][nt], 0, 0, 0);
    }

    __syncthreads();  // full drain: staged loads were issued at step TOP
  }

  // ---- denominator: 8 consecutive lanes share row pr ----
  lsum += __shfl_xor(lsum, 1);
  lsum += __shfl_xor(lsum, 2);
  lsum += __shfl_xor(lsum, 4);
  if ((lane & 7) == 0) lvv[pr] = lsum;
  __syncthreads();

  // ---- epilogue: normalize, ELU, store. C/D: row = lhi*4+reg, col = llo ----
#pragma unroll
  for (int mt = 0; mt < 2; mt++) {
#pragma unroll
    for (int reg = 0; reg < 4; reg++) {
      const int rloc = rg * 32 + mt * 16 + lhi * 4 + reg;
      const float iv = 1.f / fmaxf(lvv[rloc], 1e-35f);
      const long orow = (gr0 + rloc) * 256 + fg * 64 + llo;
#pragma unroll
      for (int nt = 0; nt < 4; nt++) {
        float v = acc[mt][nt][reg] * iv;
        v = v > 0.f ? v : expm1f(v);
        out[orow + nt * 16] = v;
      }
    }
  }
}

// ---------------------------------------------------------------------------
extern "C" void kernel_launch(void* const* d_in, const int* in_sizes, int n_in,
                              void* d_out, int out_size, void* d_ws, size_t ws_size,
                              hipStream_t stream) {
  const float* h = (const float*)d_in[0];
  const int* adj = (const int*)d_in[1];
  const float* W = (const float*)d_in[2];
  const float* a = (const float*)d_in[3];
  float* out = (float*)d_out;

  char* ws = (char*)d_ws;
  unsigned short* WhPack = (unsigned short*)ws;            //  8,388,608 B
  unsigned short* WThi = (unsigned short*)(ws + 8388608);  //    131,072 B
  unsigned short* WTlo = (unsigned short*)(ws + 8519680);  //    131,072 B
  float* s1 = (float*)(ws + 8650752);                      //     65,536 B
  float* s2 = (float*)(ws + 8716288);                      //     65,536 B
  unsigned int* s2maxEnc = (unsigned int*)(ws + 8781824);  //         32 B
  float* Wa = (float*)(ws + 8781888);                      //      2,048 B

  hipLaunchKernelGGL(k0w_split, dim3(16, 17), dim3(16, 16), 0, stream, W, a,
                     WThi, WTlo, s2maxEnc, Wa);
  hipLaunchKernelGGL(k1_mfma, dim3(256), dim3(512), 0, stream, h, WThi, WTlo, Wa,
                     WhPack, s1, s2, s2maxEnc);
  hipLaunchKernelGGL(k3_attn, dim3(256), dim3(512), 0, stream, WhPack, adj,
                     s1, s2, s2maxEnc, out);
}

// Round 10
// 242.449 us; speedup vs baseline: 1.0836x; 1.0836x over previous
//
#include <hip/hip_runtime.h>

typedef __attribute__((ext_vector_type(8))) short bhalf8;
typedef __attribute__((ext_vector_type(4))) float floatx4;

#define ALPHA_LR 0.2f

__device__ __forceinline__ unsigned short f2bf(float f) {
  union { float f; unsigned int u; } v; v.f = f;
  unsigned int r = v.u + 0x7fffu + ((v.u >> 16) & 1u);
  return (unsigned short)(r >> 16);
}
__device__ __forceinline__ float bf2f(unsigned short u) {
  union { unsigned int u; float f; } v; v.u = ((unsigned int)u) << 16;
  return v.f;
}
// async global->LDS, 16B per lane; LDS dest is wave-uniform base + lane*16
__device__ __forceinline__ void gld16(const void* g, void* l) {
  __builtin_amdgcn_global_load_lds((const __attribute__((address_space(1))) unsigned int*)g,
                                   (__attribute__((address_space(3))) unsigned int*)l,
                                   16, 0, 0);
}

// ---------------------------------------------------------------------------
// k0w: W [k][n] fp32 -> WT_hi/WT_lo bf16, k-tiled layout [ks=8][n=256][k'=32].
// Also re-initializes s2maxEnc[8] (ws is re-poisoned before every call).
// (Reverted to round-8 form.)
// ---------------------------------------------------------------------------
__global__ void k0w_split(const float* __restrict__ W,
                          unsigned short* __restrict__ WThi,
                          unsigned short* __restrict__ WTlo,
                          unsigned int* __restrict__ s2maxEnc) {
  __shared__ float s[16][17];
  const int tx = threadIdx.x, ty = threadIdx.y;
  if (blockIdx.x == 0 && blockIdx.y == 0 && ty == 0 && tx < 8) s2maxEnc[tx] = 0u;
  const int n0 = blockIdx.x * 16, k0 = blockIdx.y * 16;
  s[ty][tx] = W[(k0 + ty) * 256 + n0 + tx];
  __syncthreads();
  float v = s[tx][ty];  // = W[k0+tx][n0+ty]
  const int k = k0 + tx, n = n0 + ty;
  unsigned short hi = f2bf(v);
  unsigned short lo = f2bf(v - bf2f(hi));
  const int idx = (k >> 5) * 8192 + n * 32 + (k & 31);
  WThi[idx] = hi;
  WTlo[idx] = lo;
}

// ---------------------------------------------------------------------------
// k1 v3: round-8 k1 with ONLY the round-9-proven-safe trims applied:
//   - h staged hi-only (Al buffer + lo-split VALU deleted)
//   - TWO MFMA passes (ah*bh + ah*bl = bf16(h) x exact-W); the dropped al*bh
//     term is subdominant to WhPack's bf16 store quantum (round 9 PASSED with
//     identical absmax 0.0078125)
//   - s1/s2 epilogue UNCHANGED from round-8 (accumulator dots with a, 16-lane
//     shfl reduce, s1red/s2red atomics) -- round-9's staging-phase shfl chain
//     was the regression suspect and is NOT repeated here.
// Writes WhPack bf16 [B][jt=64][f=256][j'=32]. LDS ~97.5 KB.
// ---------------------------------------------------------------------------
__global__ __launch_bounds__(512, 2) void k1_mfma(const float* __restrict__ h,
                                                  const unsigned short* __restrict__ Bhi_g,
                                                  const unsigned short* __restrict__ Blo_g,
                                                  const float* __restrict__ a_g,
                                                  unsigned short* __restrict__ WhPack,
                                                  float* __restrict__ s1,
                                                  float* __restrict__ s2,
                                                  unsigned int* __restrict__ s2maxEnc) {
  __shared__ unsigned short Ah[64 * 264];              // 33 KB
  __shared__ unsigned short Bh[2][8192], Bl[2][8192];  // 16 KB per buffer
  __shared__ float s1red[64], s2red[64];
  const int t = threadIdx.x;
  const long r0 = (long)blockIdx.x * 64;
  const int wave = t >> 6, lane = t & 63;

  if (t < 64) { s1red[t] = 0.f; s2red[t] = 0.f; }

#pragma unroll
  for (int rep = 0; rep < 2; rep++) {
    const int off = wave * 1024 + rep * 512;
    gld16(Bhi_g + off + lane * 8, &Bh[0][off]);
    gld16(Blo_g + off + lane * 8, &Bl[0][off]);
  }

#pragma unroll
  for (int q = 0; q < 8; q++) {
    int idx = q * 512 + t;
    int row = idx >> 6, c4 = idx & 63;
    float4 x = *(const float4*)(h + (r0 + row) * 256 + c4 * 4);
    unsigned short hs[4] = {f2bf(x.x), f2bf(x.y), f2bf(x.z), f2bf(x.w)};
    *(ushort4*)&Ah[row * 264 + c4 * 4] = (ushort4){hs[0], hs[1], hs[2], hs[3]};
  }
  __syncthreads();

  const int wm = wave >> 2, wn = wave & 3;
  const int lhi = lane >> 4, llo = lane & 15;

  floatx4 acc[2][4];
#pragma unroll
  for (int mt = 0; mt < 2; mt++)
#pragma unroll
    for (int nt = 0; nt < 4; nt++) acc[mt][nt] = (floatx4){0.f, 0.f, 0.f, 0.f};

  for (int ks = 0; ks < 8; ks++) {
    const int cur = ks & 1, nxt = cur ^ 1, ksn = (ks + 1) & 7;
#pragma unroll
    for (int rep = 0; rep < 2; rep++) {
      const int off = wave * 1024 + rep * 512;
      gld16(Bhi_g + ksn * 8192 + off + lane * 8, &Bh[nxt][off]);
      gld16(Blo_g + ksn * 8192 + off + lane * 8, &Bl[nxt][off]);
    }

    const int k0 = ks * 32;
    bhalf8 ah[2], bh[4], bl[4];
#pragma unroll
    for (int mt = 0; mt < 2; mt++) {
      int ro = (wm * 32 + mt * 16 + llo) * 264 + k0 + lhi * 8;
      ah[mt] = *(const bhalf8*)&Ah[ro];
    }
#pragma unroll
    for (int nt = 0; nt < 4; nt++) {
      int ro = (wn * 64 + nt * 16 + llo) * 32 + lhi * 8;
      bh[nt] = *(const bhalf8*)&Bh[cur][ro];
      bl[nt] = *(const bhalf8*)&Bl[cur][ro];
    }
#pragma unroll
    for (int mt = 0; mt < 2; mt++)
#pragma unroll
      for (int nt = 0; nt < 4; nt++) {
        acc[mt][nt] = __builtin_amdgcn_mfma_f32_16x16x32_bf16(ah[mt], bh[nt], acc[mt][nt], 0, 0, 0);
        acc[mt][nt] = __builtin_amdgcn_mfma_f32_16x16x32_bf16(ah[mt], bl[nt], acc[mt][nt], 0, 0, 0);
      }
    __syncthreads();
  }

  float a1v[4], a2v[4];
#pragma unroll
  for (int nt = 0; nt < 4; nt++) {
    int f = wn * 64 + nt * 16 + llo;
    a1v[nt] = a_g[f];
    a2v[nt] = a_g[256 + f];
  }

  const int b = (int)(r0 >> 11);
  const int jt_base = (int)((r0 & 2047) >> 5);

#pragma unroll
  for (int mt = 0; mt < 2; mt++) {
    float p1[4], p2[4];
#pragma unroll
    for (int reg = 0; reg < 4; reg++) {
      p1[reg] = acc[mt][0][reg] * a1v[0] + acc[mt][1][reg] * a1v[1] +
                acc[mt][2][reg] * a1v[2] + acc[mt][3][reg] * a1v[3];
      p2[reg] = acc[mt][0][reg] * a2v[0] + acc[mt][1][reg] * a2v[1] +
                acc[mt][2][reg] * a2v[2] + acc[mt][3][reg] * a2v[3];
    }
#pragma unroll
    for (int off = 1; off < 16; off <<= 1) {
#pragma unroll
      for (int reg = 0; reg < 4; reg++) {
        p1[reg] += __shfl_xor(p1[reg], off);
        p2[reg] += __shfl_xor(p2[reg], off);
      }
    }
    if (llo == 0) {
#pragma unroll
      for (int reg = 0; reg < 4; reg++) {
        int il = wm * 32 + mt * 16 + lhi * 4 + reg;
        atomicAdd(&s1red[il], p1[reg]);
        atomicAdd(&s2red[il], p2[reg]);
      }
    }
#pragma unroll
    for (int nt = 0; nt < 4; nt++) {
      int f = wn * 64 + nt * 16 + llo;
      int jt = jt_base + wm;
      ushort4 pk = (ushort4){f2bf(acc[mt][nt][0]), f2bf(acc[mt][nt][1]),
                             f2bf(acc[mt][nt][2]), f2bf(acc[mt][nt][3])};
      *(ushort4*)&WhPack[((long)((b * 64 + jt) * 256 + f)) * 32 + mt * 16 + lhi * 4] = pk;
    }
  }

  __syncthreads();
  if (t < 64) {
    s1[r0 + t] = s1red[t];
    s2[r0 + t] = s2red[t];
    // per-batch max(s2): 64-lane reduce + one encoded atomicMax per block
    float v = s2red[t];
#pragma unroll
    for (int o = 32; o; o >>= 1) v = fmaxf(v, __shfl_xor(v, o));
    if (t == 0) {
      unsigned int u = __float_as_uint(v);
      unsigned int key = (u & 0x80000000u) ? ~u : (u | 0x80000000u);
      atomicMax(s2maxEnc + b, key);
    }
  }
}

// ---------------------------------------------------------------------------
// K3 v9 (unchanged): m97-structure GEMM, P computed into LDS, adj streamed
// directly (absorbed in the idle VMEM pipe; measured free).
// LDS 90.3 KB; grid 256 x 512 thr (1 block/CU); XCD-affine b = lin&7.
// ---------------------------------------------------------------------------
__global__ __launch_bounds__(512, 2) void k3_attn(const unsigned short* __restrict__ WhPack,
                                                  const int* __restrict__ adj,
                                                  const float* __restrict__ s1g,
                                                  const float* __restrict__ s2g,
                                                  const unsigned int* __restrict__ s2maxEnc,
                                                  float* __restrict__ out) {
  const int t = threadIdx.x;
  const int lin = blockIdx.x;
  const int b = lin & 7;  // XCD-affine: round-robin dispatch -> XCD = lin%8
  const int ig = lin >> 3;
  const long gr0 = (long)b * 2048 + ig * 64;

  const int wave = t >> 6, lane = t & 63;
  const int rg = wave >> 2, fg = wave & 3;  // wave tile: 32 rows x 64 f
  const int llo = lane & 15, lhi = lane >> 4;

  __shared__ unsigned short WhL[2][16384];  // 64 KB: [kk jt][f 256][j' 32] swz
  __shared__ unsigned short Pl[2][64 * 72]; // 18 KB: [row 64][j 64 pad 72]
  __shared__ float s2l[2048];               // 8 KB
  __shared__ float lvv[64];

  // ---- P-compute role: row pr (0..63), j-octet pq (0..7) ----
  const int pr = t >> 3;
  const int pq = t & 7;

  const float s1i = s1g[gr0 + pr];
  const unsigned int ek = s2maxEnc[b];
  const float s2max = (ek & 0x80000000u) ? __uint_as_float(ek & 0x7fffffffu)
                                         : __uint_as_float(~ek);
  const float xm = s1i + s2max;
  const float Mi = fmaxf(xm, ALPHA_LR * xm);
  // adj row segment for this thread: 8 ints at + (ptile)*64 + pq*8
  const int* arow = adj + (gr0 + pr) * 2048 + pq * 8;

  // ---- gld16 source (inverse-swizzled): lane-constant part ----
  // LDS linear L = i*4096 + wave*512 + lane*8 (ushort) -> f,granule; source
  // granule = (lane&3) ^ ((lane>>3)&3) so LDS[f][g] = global[f][g ^ (f>>1)&3]
  const int gsrc8 = (((lane & 3) ^ ((lane >> 3) & 3))) * 8;
  const unsigned short* wsrcB =
      WhPack + (long)b * 524288 + wave * 512 + (lane >> 2) * 32 + gsrc8;

  // ---- ds_read lane-constant offsets ----
  const int boff = fg * 2048 + llo * 32 + (lhi ^ ((llo >> 1) & 3)) * 8;  // B
  const int aoff = (rg * 32 + llo) * 72 + lhi * 8;                       // A

  // ---- prologue ----
  // stage s2 (whole batch) into LDS
  *(float4*)&s2l[t * 4] = *(const float4*)(s2g + (long)b * 2048 + t * 4);
  // stage Wh K-tile 0 (jt 0,1) into WhL[0]
#pragma unroll
  for (int i = 0; i < 4; i++)
    gld16(wsrcB + i * 4096, &WhL[0][i * 4096 + wave * 512]);
  // adj for P-tile 0 (used in prologue) and P-tile 1 (used at step 0)
  int4 a0A = *(const int4*)(arow);
  int4 a0B = *(const int4*)(arow + 4);
  int4 ajCA = *(const int4*)(arow + 64);
  int4 ajCB = *(const int4*)(arow + 68);
  __syncthreads();  // s2l ready; WhL[0] landed (vmcnt drain)

  float lsum = 0.f;
  {  // P tile 0 -> Pl[0]
    int am[8] = {a0A.x, a0A.y, a0A.z, a0A.w, a0B.x, a0B.y, a0B.z, a0B.w};
    float4 sA = *(const float4*)&s2l[pq * 8];
    float4 sB = *(const float4*)&s2l[pq * 8 + 4];
    float xs[8] = {sA.x, sA.y, sA.z, sA.w, sB.x, sB.y, sB.z, sB.w};
    unsigned int pk[4];
    float e[8];
#pragma unroll
    for (int q = 0; q < 8; q++) {
      float x = s1i + xs[q];
      float lk = fmaxf(x, ALPHA_LR * x);
      float ee = __expf(lk - Mi);
      ee = (am[q] > 0) ? ee : 0.f;
      lsum += ee;
      e[q] = ee;
    }
#pragma unroll
    for (int q = 0; q < 4; q++)
      asm("v_cvt_pk_bf16_f32 %0, %1, %2" : "=v"(pk[q]) : "v"(e[2 * q]), "v"(e[2 * q + 1]));
    *(uint4*)&Pl[0][pr * 72 + pq * 8] = (uint4){pk[0], pk[1], pk[2], pk[3]};
  }
  __syncthreads();  // Pl[0] visible

  floatx4 acc[2][4];
#pragma unroll
  for (int mt = 0; mt < 2; mt++)
#pragma unroll
    for (int nt = 0; nt < 4; nt++) acc[mt][nt] = (floatx4){0.f, 0.f, 0.f, 0.f};

#pragma unroll 2
  for (int step = 0; step < 32; step++) {
    const int cur = step & 1, nxt = cur ^ 1;

    // ---- issue: stage next Wh K-tile + adj for P-tile step+2 ----
    if (step < 31) {
      const long jb = (long)(step + 1) * 16384;  // (step+1)*2 jt * 8192
#pragma unroll
      for (int i = 0; i < 4; i++)
        gld16(wsrcB + jb + i * 4096, &WhL[nxt][i * 4096 + wave * 512]);
    }
    const int tp = (step < 30 ? step + 2 : 31) * 64;
    int4 ajNA = *(const int4*)(arow + tp);
    int4 ajNB = *(const int4*)(arow + tp + 4);
    __builtin_amdgcn_sched_barrier(0);

    // ---- compute P for tile step+1 -> Pl[nxt] ----
    if (step < 31) {
      int am[8] = {ajCA.x, ajCA.y, ajCA.z, ajCA.w, ajCB.x, ajCB.y, ajCB.z, ajCB.w};
      const int sbase = (step + 1) * 64 + pq * 8;
      float4 sA = *(const float4*)&s2l[sbase];
      float4 sB = *(const float4*)&s2l[sbase + 4];
      float xs[8] = {sA.x, sA.y, sA.z, sA.w, sB.x, sB.y, sB.z, sB.w};
      unsigned int pk[4];
      float e[8];
#pragma unroll
      for (int q = 0; q < 8; q++) {
        float x = s1i + xs[q];
        float lk = fmaxf(x, ALPHA_LR * x);
        float ee = __expf(lk - Mi);
        ee = (am[q] > 0) ? ee : 0.f;
        lsum += ee;
        e[q] = ee;
      }
#pragma unroll
      for (int q = 0; q < 4; q++)
        asm("v_cvt_pk_bf16_f32 %0, %1, %2" : "=v"(pk[q]) : "v"(e[2 * q]), "v"(e[2 * q + 1]));
      *(uint4*)&Pl[nxt][pr * 72 + pq * 8] = (uint4){pk[0], pk[1], pk[2], pk[3]};
    }
    ajCA = ajNA; ajCB = ajNB;

    // ---- MFMA on current buffers: kk2 x (mt2 x nt4) ----
#pragma unroll
    for (int kk = 0; kk < 2; kk++) {
      bhalf8 aF[2], bF[4];
#pragma unroll
      for (int mt = 0; mt < 2; mt++)
        aF[mt] = *(const bhalf8*)&Pl[cur][aoff + mt * 1152 + kk * 32];
#pragma unroll
      for (int nt = 0; nt < 4; nt++)
        bF[nt] = *(const bhalf8*)&WhL[cur][kk * 8192 + nt * 512 + boff];
#pragma unroll
      for (int mt = 0; mt < 2; mt++)
#pragma unroll
        for (int nt = 0; nt < 4; nt++)
          acc[mt][nt] = __builtin_amdgcn_mfma_f32_16x16x32_bf16(aF[mt], bF[nt], acc[mt][nt], 0, 0, 0);
    }

    __syncthreads();  // full drain: staged loads were issued at step TOP
  }

  // ---- denominator: 8 consecutive lanes share row pr ----
  lsum += __shfl_xor(lsum, 1);
  lsum += __shfl_xor(lsum, 2);
  lsum += __shfl_xor(lsum, 4);
  if ((lane & 7) == 0) lvv[pr] = lsum;
  __syncthreads();

  // ---- epilogue: normalize, ELU, store. C/D: row = lhi*4+reg, col = llo ----
#pragma unroll
  for (int mt = 0; mt < 2; mt++) {
#pragma unroll
    for (int reg = 0; reg < 4; reg++) {
      const int rloc = rg * 32 + mt * 16 + lhi * 4 + reg;
      const float iv = 1.f / fmaxf(lvv[rloc], 1e-35f);
      const long orow = (gr0 + rloc) * 256 + fg * 64 + llo;
#pragma unroll
      for (int nt = 0; nt < 4; nt++) {
        float v = acc[mt][nt][reg] * iv;
        v = v > 0.f ? v : expm1f(v);
        out[orow + nt * 16] = v;
      }
    }
  }
}

// ---------------------------------------------------------------------------
extern "C" void kernel_launch(void* const* d_in, const int* in_sizes, int n_in,
                              void* d_out, int out_size, void* d_ws, size_t ws_size,
                              hipStream_t stream) {
  const float* h = (const float*)d_in[0];
  const int* adj = (const int*)d_in[1];
  const float* W = (const float*)d_in[2];
  const float* a = (const float*)d_in[3];
  float* out = (float*)d_out;

  char* ws = (char*)d_ws;
  unsigned short* WhPack = (unsigned short*)ws;            //  8,388,608 B
  unsigned short* WThi = (unsigned short*)(ws + 8388608);  //    131,072 B
  unsigned short* WTlo = (unsigned short*)(ws + 8519680);  //    131,072 B
  float* s1 = (float*)(ws + 8650752);                      //     65,536 B
  float* s2 = (float*)(ws + 8716288);                      //     65,536 B
  unsigned int* s2maxEnc = (unsigned int*)(ws + 8781824);  //         32 B

  hipLaunchKernelGGL(k0w_split, dim3(16, 16), dim3(16, 16), 0, stream, W, WThi, WTlo, s2maxEnc);
  hipLaunchKernelGGL(k1_mfma, dim3(256), dim3(512), 0, stream, h, WThi, WTlo, a,
                     WhPack, s1, s2, s2maxEnc);
  hipLaunchKernelGGL(k3_attn, dim3(256), dim3(512), 0, stream, WhPack, adj,
                     s1, s2, s2maxEnc, out);
}